// Round 6
// baseline (1161.658 us; speedup 1.0000x reference)
//
#include <hip/hip_runtime.h>

typedef unsigned short u16;
typedef __attribute__((ext_vector_type(8))) short short8;
typedef __attribute__((ext_vector_type(4))) float floatx4;

#define NN_TOT 135168   // 4096 * 33

// ---- compile-time skeleton (from SKELETON_EDGES, incl. self-loops) ----
static constexpr int NBCNT[33] = {2,2,2,2,2,2,2,1,1,1,1,3,3,2,2,4,4,2,2,2,2,1,1,3,3,2,2,3,3,2,2,2,2};
static constexpr int NBR[33][4] = {
 {1,4,0,0},{0,2,0,0},{1,3,0,0},{2,7,0,0},{0,5,0,0},{4,6,0,0},{5,8,0,0},
 {3,0,0,0},{6,0,0,0},{10,0,0,0},{9,0,0,0},
 {12,13,23,0},{11,14,24,0},{11,15,0,0},{12,16,0,0},
 {13,17,19,21},{14,18,20,22},
 {15,19,0,0},{16,20,0,0},{15,17,0,0},{16,18,0,0},{15,0,0,0},{16,0,0,0},
 {11,24,25,0},{12,23,26,0},{23,27,0,0},{24,28,0,0},
 {25,29,31,0},{26,30,32,0},{27,31,0,0},{28,32,0,0},{29,27,0,0},{30,28,0,0}};
static constexpr float R2 = 0.70710678f, R3 = 0.57735027f, R4 = 0.5f, R5 = 0.44721360f;
static constexpr float DINV[33] = {R3,R3,R3,R3,R3,R3,R3, R2,R2,R2,R2, R4,R4, R3,R3, R5,R5,
                                   R3,R3,R3,R3, R2,R2, R4,R4, R3,R3, R4,R4, R3,R3,R3,R3};

__device__ __forceinline__ float bf2f(u16 u) {
  unsigned int v = ((unsigned int)u) << 16; float f; __builtin_memcpy(&f, &v, 4); return f;
}
__device__ __forceinline__ u16 f2bf(float f) {
  unsigned int u; __builtin_memcpy(&u, &f, 4);
  return (u16)((u + 0x7fffu + ((u >> 16) & 1u)) >> 16);
}
__device__ __forceinline__ float ldin(const void* p, int i, int isbf) {
  return isbf ? bf2f(((const u16*)p)[i]) : ((const float*)p)[i];
}

// ---- dtype detector ----
__global__ __launch_bounds__(256) void detect_kernel(const u16* __restrict__ x,
                                                     int* __restrict__ flag)
{
  __shared__ int cnt[256];
  const int t = threadIdx.x;
  int c = 0;
  for (int j = 0; j < 16; ++j) {
    u16 u = x[(t*16 + j)*2];
    int e = (u >> 7) & 0xFF;
    c += (e >= 118 && e <= 130) ? 1 : 0;
  }
  cnt[t] = c;
  __syncthreads();
  if (t == 0) {
    int s = 0;
    for (int i = 0; i < 256; ++i) s += cnt[i];
    *flag = (s > 2048) ? 1 : 0;   // 1 = bf16 inputs, 0 = fp32 inputs
  }
}

// ---- prep: blocks 0..47 transpose W; blocks 48..112 init wq/bq + zero repl ----
__global__ __launch_bounds__(256) void prep_kernel(const void* __restrict__ w0,
    const void* __restrict__ w1, const void* __restrict__ w2, u16* __restrict__ Wt,
    const void* __restrict__ wh, const void* __restrict__ bh,
    const void* __restrict__ wc, const void* __restrict__ bc,
    float* __restrict__ wq, float* __restrict__ bq, float* __restrict__ repl,
    const int* __restrict__ flag)
{
  const int isbf = *flag;
  const int t = threadIdx.x;
  const int lane = t & 63;
  if (blockIdx.x < 48) {
    const int m = blockIdx.x >> 4;
    const int nb = (blockIdx.x & 15) * 16;
    const void* W = m == 0 ? w0 : (m == 1 ? w1 : w2);
    u16* O = Wt + (size_t)m * 65536;
    const int wv = t >> 6;
#pragma unroll
    for (int nn = 0; nn < 4; ++nn) {
      const int n = nb + nn*4 + wv;
#pragma unroll
      for (int j = 0; j < 4; ++j) {
        const int k = lane + 64*j;
        O[n*256 + k] = isbf ? ((const u16*)W)[k*256 + n] : f2bf(((const float*)W)[k*256 + n]);
      }
    }
  } else {
    const int b = blockIdx.x - 48;   // 0..64
    for (int i = b*256 + t; i < 3*64*512; i += 65*256) repl[i] = 0.f;
    if (b < 64) {
      const int r = b*4 + (t >> 6);
      float a0=0.f, a1=0.f, a2=0.f, a3=0.f;
#pragma unroll
      for (int j = 0; j < 4; ++j) {
        const int k = lane + 64*j;
        const float w = ldin(wh, r*256 + k, isbf);
        a0 += w*ldin(wc, k*4+0, isbf); a1 += w*ldin(wc, k*4+1, isbf);
        a2 += w*ldin(wc, k*4+2, isbf); a3 += w*ldin(wc, k*4+3, isbf);
      }
#pragma unroll
      for (int off = 32; off; off >>= 1) {
        a0 += __shfl_xor(a0, off); a1 += __shfl_xor(a1, off);
        a2 += __shfl_xor(a2, off); a3 += __shfl_xor(a3, off);
      }
      if (lane == 0) { wq[r*4+0]=a0; wq[r*4+1]=a1; wq[r*4+2]=a2; wq[r*4+3]=a3; }
    } else if (t < 64) {
      float s0=0.f, s1=0.f, s2=0.f, s3=0.f;
#pragma unroll
      for (int j = 0; j < 4; ++j) {
        const int k = lane + 64*j;
        const float bb = ldin(bh, k, isbf);
        s0 += bb*ldin(wc, k*4+0, isbf); s1 += bb*ldin(wc, k*4+1, isbf);
        s2 += bb*ldin(wc, k*4+2, isbf); s3 += bb*ldin(wc, k*4+3, isbf);
      }
#pragma unroll
      for (int off = 32; off; off >>= 1) {
        s0 += __shfl_xor(s0, off); s1 += __shfl_xor(s1, off);
        s2 += __shfl_xor(s2, off); s3 += __shfl_xor(s3, off);
      }
      if (lane == 0) {
        bq[0] = s0 + ldin(bc, 0, isbf); bq[1] = s1 + ldin(bc, 1, isbf);
        bq[2] = s2 + ldin(bc, 2, isbf); bq[3] = s3 + ldin(bc, 3, isbf);
      }
    }
  }
}

// ---- FUSED GCN layer, barrier-free K-loop ----
// H_out = (Ahat @ act(A_in)) @ W + b, BN stats to repl.
// 320 threads = 5 waves; wave wv owns rows wv*16..wv*16+15 of a 66-row stripe
// (2 whole graphs) x all 256 cols. A-fragments are gathered per-lane directly
// from global (agg sources block-confined => in-place safe with the single
// pre-epilogue __syncthreads). B-fragments read directly from L2-resident Wt.
template<int ACT>
__global__ __launch_bounds__(320, 3) void gcn_kernel(
    const void* __restrict__ Ain, const u16* __restrict__ Bt,
    const float* __restrict__ fscale, const float* __restrict__ fshift,
    const void* __restrict__ bias, u16* __restrict__ Hout,
    float* __restrict__ repl, const int* __restrict__ flag)
{
  __shared__ float sS[512];          // block-level stat reduction (s1 || s2)
  const int tid = threadIdx.x;
  const int lane = tid & 63, wv = tid >> 6;
  const int fr = lane & 15, q = lane >> 4;
  const int isbf = (ACT == 0) ? *flag : 1;
  const size_t row0 = (size_t)blockIdx.x * 66;

  for (int i = tid; i < 512; i += 320) sS[i] = 0.f;

  // per-lane aggregation sources for row rl = wv*16 + fr
  const int rl = wv*16 + fr;
  const bool valid = (rl < 66);
  const int node = valid ? (rl % 33) : 0;
  const int gb = valid ? ((rl / 33) * 33) : 0;
  int off[5]; float wt[5];
  {
    const float di = DINV[node];
    off[0] = (gb + node) * 256; wt[0] = valid ? di*di : 0.f;
    const int cnt = NBCNT[node];
#pragma unroll
    for (int j = 0; j < 4; ++j) {
      const int s = NBR[node][j];
      const bool u = valid && (j < cnt);
      off[j+1] = u ? (gb + s)*256 : 0;
      wt[j+1]  = u ? di*DINV[s] : 0.f;
    }
  }

  floatx4 acc[16];
#pragma unroll
  for (int nt = 0; nt < 16; ++nt) acc[nt] = (floatx4){0.f,0.f,0.f,0.f};

  const u16* Ab = (const u16*)Ain + row0*256;
  const float* Af = (const float*)Ain + row0*256;

  for (int kc = 0; kc < 8; ++kc) {
    const int k0 = kc*32 + q*8;
    float av[8];
#pragma unroll
    for (int e = 0; e < 8; ++e) av[e] = 0.f;
    if (ACT == 1) {
      float4 sc0 = *(const float4*)(fscale + k0);
      float4 sc1 = *(const float4*)(fscale + k0 + 4);
      float4 sh0 = *(const float4*)(fshift + k0);
      float4 sh1 = *(const float4*)(fshift + k0 + 4);
      const float scv[8] = {sc0.x,sc0.y,sc0.z,sc0.w,sc1.x,sc1.y,sc1.z,sc1.w};
      const float shv[8] = {sh0.x,sh0.y,sh0.z,sh0.w,sh1.x,sh1.y,sh1.z,sh1.w};
#pragma unroll
      for (int j = 0; j < 5; ++j) {
        uint4 p = *(const uint4*)(Ab + off[j] + k0);
        const u16* us = (const u16*)&p;
        const float w = wt[j];
#pragma unroll
        for (int e = 0; e < 8; ++e)
          av[e] += w * fmaxf(0.f, fmaf(bf2f(us[e]), scv[e], shv[e]));
      }
    } else if (isbf) {
#pragma unroll
      for (int j = 0; j < 5; ++j) {
        uint4 p = *(const uint4*)(Ab + off[j] + k0);
        const u16* us = (const u16*)&p;
        const float w = wt[j];
#pragma unroll
        for (int e = 0; e < 8; ++e) av[e] += w * bf2f(us[e]);
      }
    } else {
#pragma unroll
      for (int j = 0; j < 5; ++j) {
        float4 p0 = *(const float4*)(Af + off[j] + k0);
        float4 p1 = *(const float4*)(Af + off[j] + k0 + 4);
        const float w = wt[j];
        av[0]+=w*p0.x; av[1]+=w*p0.y; av[2]+=w*p0.z; av[3]+=w*p0.w;
        av[4]+=w*p1.x; av[5]+=w*p1.y; av[6]+=w*p1.z; av[7]+=w*p1.w;
      }
    }
    u16 ov[8];
#pragma unroll
    for (int e = 0; e < 8; ++e) ov[e] = f2bf(av[e]);
    short8 a;
    __builtin_memcpy(&a, ov, 16);
#pragma unroll
    for (int nt = 0; nt < 16; ++nt) {
      short8 b = *(const short8*)(Bt + (nt*16 + fr)*256 + kc*32 + q*8);
      acc[nt] = __builtin_amdgcn_mfma_f32_16x16x32_bf16(a, b, acc[nt], 0, 0, 0);
    }
  }

  __syncthreads();   // all in-place reads done; sS zeros visible

  const int flagv = *flag;
  float s1[16], s2[16];
#pragma unroll
  for (int nt = 0; nt < 16; ++nt) { s1[nt] = 0.f; s2[nt] = 0.f; }
#pragma unroll
  for (int nt = 0; nt < 16; ++nt) {
    const int col = nt*16 + fr;
    const float bv = ldin(bias, col, flagv);
#pragma unroll
    for (int rr = 0; rr < 4; ++rr) {
      const int row = wv*16 + q*4 + rr;   // C-frag: col=lane&15, row=q*4+reg
      if (row < 66) {
        const float h = acc[nt][rr] + bv;
        Hout[(row0 + row)*256 + col] = f2bf(h);
        s1[nt] += h; s2[nt] += h*h;
      }
    }
  }
#pragma unroll
  for (int nt = 0; nt < 16; ++nt) {
    s1[nt] += __shfl_xor(s1[nt], 16); s1[nt] += __shfl_xor(s1[nt], 32);
    s2[nt] += __shfl_xor(s2[nt], 16); s2[nt] += __shfl_xor(s2[nt], 32);
  }
  if (lane < 16) {
#pragma unroll
    for (int nt = 0; nt < 16; ++nt) {
      atomicAdd(&sS[nt*16 + fr], s1[nt]);
      atomicAdd(&sS[256 + nt*16 + fr], s2[nt]);
    }
  }
  __syncthreads();
  float* r1 = repl + (size_t)(blockIdx.x & 63) * 512;
  for (int i = tid; i < 512; i += 320) atomicAdd(r1 + i, sS[i]);
}

// ---- finalize BN stats -> scale/shift ----
__global__ __launch_bounds__(256) void statfin_kernel(const float* __restrict__ repl,
    const void* __restrict__ gamma, const void* __restrict__ beta, float* __restrict__ fs,
    const int* __restrict__ flag)
{
  const int c = threadIdx.x;
  const int isbf = *flag;
  float s1 = 0.f, s2 = 0.f;
  for (int r = 0; r < 64; ++r) { s1 += repl[r*512 + c]; s2 += repl[r*512 + 256 + c]; }
  const float inv = 1.f / (float)NN_TOT;
  const float mu = s1 * inv;
  const float var = s2 * inv - mu*mu;
  const float rs = rsqrtf(var + 1e-5f);
  const float sc = rs * ldin(gamma, c, isbf);
  fs[c] = sc;
  fs[256 + c] = ldin(beta, c, isbf) - mu * sc;
}

// ---- fused layer3 + mean-pool + classifier ----
__global__ __launch_bounds__(256) void final_kernel(const u16* __restrict__ H,
    const float* __restrict__ fs, const float* __restrict__ wq,
    const float* __restrict__ bq, void* __restrict__ outp,
    const int* __restrict__ flag)
{
  __shared__ u16 sH[33*256];
  const int g = blockIdx.x, c = threadIdx.x;
  const int isbf = *flag;
  const uint4* src = (const uint4*)(H + (size_t)g * (33*256));
#pragma unroll
  for (int i = 0; i < 5; ++i) {
    const int idx = i*256 + c;
    if (idx < 1056) ((uint4*)sH)[idx] = src[idx];
  }
  __syncthreads();
  const float sc = fs[c], sh = fs[256 + c];
  float v = 0.f;
#pragma unroll
  for (int s = 0; s < 33; ++s) {
    float a = DINV[s];
#pragma unroll
    for (int i = 0; i < NBCNT[s]; ++i) a += DINV[NBR[s][i]];
    const float w = DINV[s] * a * (1.f/33.f);   // column-sum of Ahat / 33
    float x = bf2f(sH[s*256 + c]);
    x = fmaxf(0.f, fmaf(x, sc, sh));
    v += w * x;
  }
  float p0 = v*wq[c*4+0], p1 = v*wq[c*4+1], p2 = v*wq[c*4+2], p3 = v*wq[c*4+3];
#pragma unroll
  for (int off = 32; off; off >>= 1) {
    p0 += __shfl_xor(p0, off);
    p1 += __shfl_xor(p1, off);
    p2 += __shfl_xor(p2, off);
    p3 += __shfl_xor(p3, off);
  }
  __shared__ float sred[4][4];
  const int lane = c & 63, wid = c >> 6;
  if (lane == 0) { sred[wid][0]=p0; sred[wid][1]=p1; sred[wid][2]=p2; sred[wid][3]=p3; }
  __syncthreads();
  if (c < 4) {
    float r = sred[0][c] + sred[1][c] + sred[2][c] + sred[3][c] + bq[c];
    if (isbf) ((u16*)outp)[(size_t)g*4 + c] = f2bf(r);
    else      ((float*)outp)[(size_t)g*4 + c] = r;
  }
}

extern "C" void kernel_launch(void* const* d_in, const int* in_sizes, int n_in,
                              void* d_out, int out_size, void* d_ws, size_t ws_size,
                              hipStream_t stream)
{
  const void* x   = d_in[0];
  const void* w0  = d_in[1];
  const void* b0  = d_in[2];
  const void* g0  = d_in[3];
  const void* be0 = d_in[4];
  const void* w1  = d_in[5];
  const void* b1  = d_in[6];
  const void* g1  = d_in[7];
  const void* be1 = d_in[8];
  const void* w2  = d_in[9];
  const void* b2  = d_in[10];
  const void* g2  = d_in[11];
  const void* be2 = d_in[12];
  const void* wh  = d_in[13];
  const void* bh  = d_in[14];
  const void* wc  = d_in[15];
  const void* bc  = d_in[16];

  // Workspace: 66.8 MB total.
  char* ws = (char*)d_ws;
  float* wq   = (float*)(ws + 0);          // 1024 f
  float* bq   = (float*)(ws + 4096);       // 4 f
  float* fs   = (float*)(ws + 4608);       // 3 * 512 f
  int*   flag = (int*)  (ws + 12288);      // dtype flag
  float* repl = (float*)(ws + 16384);      // 3 * 64 * 512 f
  u16*   Wt   = (u16*)  (ws + 409600);     // 3 * 65536 bf16
  u16*   A    = (u16*)  (ws + 802816);     // 135168*256 bf16
  (void)in_sizes; (void)n_in; (void)out_size; (void)ws_size;

  detect_kernel<<<1, 256, 0, stream>>>((const u16*)x, flag);
  prep_kernel<<<113, 256, 0, stream>>>(w0, w1, w2, Wt, wh, bh, wc, bc, wq, bq, repl, flag);

  // layer 0: H0 = (Ahat @ x) @ W0 + b0
  gcn_kernel<0><<<2048, 320, 0, stream>>>(x, Wt, nullptr, nullptr, b0, A, repl, flag);
  statfin_kernel<<<1, 256, 0, stream>>>(repl, g0, be0, fs, flag);
  // layer 1 (in-place)
  gcn_kernel<1><<<2048, 320, 0, stream>>>(A, Wt + 65536, fs, fs + 256, b1, A, repl + 32768, flag);
  statfin_kernel<<<1, 256, 0, stream>>>(repl + 32768, g1, be1, fs + 512, flag);
  // layer 2 (in-place)
  gcn_kernel<1><<<2048, 320, 0, stream>>>(A, Wt + 131072, fs + 512, fs + 768, b2, A, repl + 65536, flag);
  statfin_kernel<<<1, 256, 0, stream>>>(repl + 65536, g2, be2, fs + 1024, flag);
  // layer 3 + pool + classifier (folded)
  final_kernel<<<4096, 256, 0, stream>>>(A, fs + 1024, wq, bq, d_out, flag);
}